// Round 3
// baseline (2219.288 us; speedup 1.0000x reference)
//
#include <hip/hip_runtime.h>

// ============================================================================
// CNF log-density, fused persistent kernel — Round 3.
// vs R2 (spill-bound: FETCH 2.7GB of scratch thrash): halve live registers.
//   - N-half split: 8 n-tiles of accumulators at a time (64 regs, not 128).
//   - A-frags hybrid: k-tiles 0..3 in regs (32), k-tiles 4..7 stay in LDS,
//     ds_read_b128 per kt inside the MFMA loop.
//   - RK k-vectors as packed bf16 in REGISTERS (40 regs), no LDS slots.
//   - Single feval instantiation (stage-coefficient tables) for I-cache.
//   - No __syncthreads anywhere; waves independent; B frags straight from
//     L2-resident fragment-linear bf16 weights (coalesced 1KB/instr).
//   - 128-thr blocks (2 waves), 33,792 B LDS -> 4 blocks/CU, 2 waves/SIMD,
//     grid 1024 blocks = fully resident.
// ============================================================================

#define DIM   64
#define HID   256
#define BATCH 32768
#define LOG2PI_HALF_SUM 58.8120661251f   // 32 * log(2*pi)

typedef float  floatx4 __attribute__((ext_vector_type(4)));
typedef short  short8  __attribute__((ext_vector_type(8)));

// ---- workspace layout (bytes): bf16 fragment-linear weights + fp32 biases
#define W1OFF 0          // 2 kt * 16 nt * 1KB  = 32768
#define W2OFF 32768      // 8 kt * 16 nt * 1KB  = 131072
#define W3OFF 163840     // 131072
#define W4OFF 294912     // 8 kt * 4 nt * 1KB   = 32768
#define BOFF  327680     // biases fp32: b1[256] b2[256] b3[256] b4[64]

// ---- LDS layout: per wave, two A-source buffers (value h, tangent) ----
#define TBROW 264                        // shorts per row (256 + 8 pad)
#define ABUF  8448                       // 16 rows * 264 * 2B
#define WAVE_LDS (2 * ABUF)              // 16896
#define SMEM_BYTES (2 * WAVE_LDS)        // 33792 (2 waves/block)

__device__ __forceinline__ short f2bf(float f) {
    union { float f; unsigned u; } v; v.f = f;
    unsigned r = v.u + 0x7FFFu + ((v.u >> 16) & 1u);   // RTNE
    return (short)(r >> 16);
}
__device__ __forceinline__ float bf2f(short s) {
    union { unsigned u; float f; } v; v.u = ((unsigned)(unsigned short)s) << 16;
    return v.f;
}
__device__ __forceinline__ float fast_tanh(float x) {
    float e = __expf(2.0f * x);
    return 1.0f - 2.0f * __builtin_amdgcn_rcpf(e + 1.0f);
}

// Hidden-layer epilogue for one N-half: tanh in place, write bf16 h (value)
// and (1-h^2)*t (tangent) into the wave-private A-source buffers.
__device__ __forceinline__ void act_store(floatx4* av, floatx4* at,
                                          short* vb, short* tb,
                                          int nh, int m, int kq) {
#pragma unroll
    for (int nt = 0; nt < 8; nt++)
#pragma unroll
        for (int i = 0; i < 4; i++) {
            float hv = fast_tanh(av[nt][i]);
            av[nt][i] = hv;                       // keep h for tangent scale
            vb[(kq * 4 + i) * TBROW + nh * 128 + nt * 16 + m] = f2bf(hv);
        }
#pragma unroll
    for (int nt = 0; nt < 8; nt++)
#pragma unroll
        for (int i = 0; i < 4; i++) {
            float tv = (1.0f - av[nt][i] * av[nt][i]) * at[nt][i];
            tb[(kq * 4 + i) * TBROW + nh * 128 + nt * 16 + m] = f2bf(tv);
        }
}

// One ODE f-eval. dz left as fp32 in vb (stride 68 floats); returns div for
// row (lane&15), replicated across quads. B frags straight from global (L2).
__device__ __forceinline__ float feval(short8 z0, short8 z1, short8 e0, short8 e1,
                                       const char* __restrict__ ws,
                                       short* vb, short* tb) {
    const int lane = threadIdx.x & 63;
    const int m = lane & 15, kq = lane >> 4;
    const float* bias = (const float*)(ws + BOFF);
    float* vbf = (float*)vb;
    float* tbf = (float*)tb;

    short8 AvL[4], AtL[4];       // lo-k A-frags in regs; hi-k live in LDS
    const floatx4 zero4 = {0.f, 0.f, 0.f, 0.f};

    // ---------------- layer 1: K=64 (2 kt), N=256, 2 halves ----------------
    {
        const short8* wb = (const short8*)(ws + W1OFF);
#pragma unroll
        for (int nh = 0; nh < 2; nh++) {
            floatx4 av[8], at[8];
#pragma unroll
            for (int nt = 0; nt < 8; nt++) {
                float b = bias[(nh * 8 + nt) * 16 + m];
                floatx4 bv = {b, b, b, b};
                av[nt] = bv; at[nt] = zero4;
            }
#pragma unroll
            for (int kt = 0; kt < 2; kt++) {
                short8 a_v = kt ? z1 : z0;
                short8 a_t = kt ? e1 : e0;
#pragma unroll
                for (int nt = 0; nt < 8; nt++) {
                    short8 b = wb[(kt * 16 + nh * 8 + nt) * 64 + lane];
                    av[nt] = __builtin_amdgcn_mfma_f32_16x16x32_bf16(a_v, b, av[nt], 0, 0, 0);
                    at[nt] = __builtin_amdgcn_mfma_f32_16x16x32_bf16(a_t, b, at[nt], 0, 0, 0);
                }
            }
            act_store(av, at, vb, tb, nh, m, kq);
        }
#pragma unroll
        for (int kt = 0; kt < 4; kt++) {
            AvL[kt] = *(const short8*)&vb[m * TBROW + kt * 32 + kq * 8];
            AtL[kt] = *(const short8*)&tb[m * TBROW + kt * 32 + kq * 8];
        }
    }

    // ---------------- layers 2,3: K=256 (8 kt), N=256, 2 halves ------------
#pragma unroll 1
    for (int layer = 0; layer < 2; layer++) {
        const short8* wb = (const short8*)(ws + (layer ? W3OFF : W2OFF));
        const float* bb = bias + 256 + layer * 256;
#pragma unroll
        for (int nh = 0; nh < 2; nh++) {
            floatx4 av[8], at[8];
#pragma unroll
            for (int nt = 0; nt < 8; nt++) {
                float b = bb[(nh * 8 + nt) * 16 + m];
                floatx4 bv = {b, b, b, b};
                av[nt] = bv; at[nt] = zero4;
            }
#pragma unroll
            for (int kt = 0; kt < 4; kt++) {       // lo-k: frags from regs
#pragma unroll
                for (int nt = 0; nt < 8; nt++) {
                    short8 b = wb[(kt * 16 + nh * 8 + nt) * 64 + lane];
                    av[nt] = __builtin_amdgcn_mfma_f32_16x16x32_bf16(AvL[kt], b, av[nt], 0, 0, 0);
                    at[nt] = __builtin_amdgcn_mfma_f32_16x16x32_bf16(AtL[kt], b, at[nt], 0, 0, 0);
                }
            }
#pragma unroll
            for (int kt = 4; kt < 8; kt++) {       // hi-k: frags from LDS
                short8 Ah = *(const short8*)&vb[m * TBROW + kt * 32 + kq * 8];
                short8 Th = *(const short8*)&tb[m * TBROW + kt * 32 + kq * 8];
#pragma unroll
                for (int nt = 0; nt < 8; nt++) {
                    short8 b = wb[(kt * 16 + nh * 8 + nt) * 64 + lane];
                    av[nt] = __builtin_amdgcn_mfma_f32_16x16x32_bf16(Ah, b, av[nt], 0, 0, 0);
                    at[nt] = __builtin_amdgcn_mfma_f32_16x16x32_bf16(Th, b, at[nt], 0, 0, 0);
                }
            }
            act_store(av, at, vb, tb, nh, m, kq);  // nh0 writes cols 0..127:
        }                                          //  disjoint from hi-k reads
#pragma unroll
        for (int kt = 0; kt < 4; kt++) {           // new lo-k frags -> regs
            AvL[kt] = *(const short8*)&vb[m * TBROW + kt * 32 + kq * 8];
            AtL[kt] = *(const short8*)&tb[m * TBROW + kt * 32 + kq * 8];
        }
    }

    // ---------------- layer 4: K=256 (8 kt), N=64 ----------------
    floatx4 a4v[4], a4t[4];
    {
        const short8* wb = (const short8*)(ws + W4OFF);
#pragma unroll
        for (int nt = 0; nt < 4; nt++) {
            float b = bias[768 + nt * 16 + m];
            floatx4 bv = {b, b, b, b};
            a4v[nt] = bv; a4t[nt] = zero4;
        }
#pragma unroll
        for (int kt = 0; kt < 4; kt++) {
#pragma unroll
            for (int nt = 0; nt < 4; nt++) {
                short8 b = wb[(kt * 4 + nt) * 64 + lane];
                a4v[nt] = __builtin_amdgcn_mfma_f32_16x16x32_bf16(AvL[kt], b, a4v[nt], 0, 0, 0);
                a4t[nt] = __builtin_amdgcn_mfma_f32_16x16x32_bf16(AtL[kt], b, a4t[nt], 0, 0, 0);
            }
        }
#pragma unroll
        for (int kt = 4; kt < 8; kt++) {
            short8 Ah = *(const short8*)&vb[m * TBROW + kt * 32 + kq * 8];
            short8 Th = *(const short8*)&tb[m * TBROW + kt * 32 + kq * 8];
#pragma unroll
            for (int nt = 0; nt < 4; nt++) {
                short8 b = wb[(kt * 4 + nt) * 64 + lane];
                a4v[nt] = __builtin_amdgcn_mfma_f32_16x16x32_bf16(Ah, b, a4v[nt], 0, 0, 0);
                a4t[nt] = __builtin_amdgcn_mfma_f32_16x16x32_bf16(Th, b, a4t[nt], 0, 0, 0);
            }
        }
    }

    // Jeps: C->A layout via tb-as-float scratch, dot with bf16 eps frags
#pragma unroll
    for (int nt = 0; nt < 4; nt++)
#pragma unroll
        for (int i = 0; i < 4; i++)
            tbf[(kq * 4 + i) * 68 + nt * 16 + m] = a4t[nt][i];
    float div = 0.f;
#pragma unroll
    for (int kt2 = 0; kt2 < 2; kt2++) {
        short8 ee = kt2 ? e1 : e0;
#pragma unroll
        for (int jj = 0; jj < 8; jj += 4) {
            floatx4 jv = *(const floatx4*)&tbf[m * 68 + kt2 * 32 + kq * 8 + jj];
            div += jv.x * bf2f(ee[jj])     + jv.y * bf2f(ee[jj + 1])
                 + jv.z * bf2f(ee[jj + 2]) + jv.w * bf2f(ee[jj + 3]);
        }
    }
    div += __shfl_xor(div, 16, 64);
    div += __shfl_xor(div, 32, 64);

    // dz -> vb-as-float for the caller to read back in A-frag layout
#pragma unroll
    for (int nt = 0; nt < 4; nt++)
#pragma unroll
        for (int i = 0; i < 4; i++)
            vbf[(kq * 4 + i) * 68 + nt * 16 + m] = a4v[nt][i];
    return div;
}

__global__ void __launch_bounds__(128, 2)
cnf_main(const float* __restrict__ x, const float* __restrict__ eps,
         const char* __restrict__ ws, float* __restrict__ out) {
    extern __shared__ char smem[];
    const int tid  = threadIdx.x;
    const int lane = tid & 63;
    const int wave = tid >> 6;
    const int m = lane & 15, kq = lane >> 4;
    const int row = blockIdx.x * 32 + wave * 16 + m;
    short* vb = (short*)(smem + wave * WAVE_LDS);
    short* tb = vb + ABUF / 2;               // ABUF bytes after vb
    float* vbf = (float*)vb;

    float y[16];
    short8 e0, e1;
#pragma unroll
    for (int kt = 0; kt < 2; kt++)
#pragma unroll
        for (int q = 0; q < 2; q++) {
            floatx4 vx = *(const floatx4*)(x   + row * DIM + kt * 32 + kq * 8 + q * 4);
            floatx4 ve = *(const floatx4*)(eps + row * DIM + kt * 32 + kq * 8 + q * 4);
#pragma unroll
            for (int j = 0; j < 4; j++) {
                y[kt * 8 + q * 4 + j] = vx[j];
                short be = f2bf(ve[j]);
                if (kt == 0) e0[q * 4 + j] = be; else e1[q * 4 + j] = be;
            }
        }

    float ylogp = 0.f;
    float K[16], zs[16];
    short8 z0, z1;
    short8 Ks[5][2];                          // packed bf16 k1..k5 (40 VGPRs)

    // DOPRI5 coefficients with h=0.25 folded in; hA[s][j] = coeff of k_{j+1}
    // in the z for stage s+2 (diagonal at j==s). hB = output weights.
    const float hA[5][5] = {
        {0.05f, 0.f, 0.f, 0.f, 0.f},
        {0.01875f, 0.05625f, 0.f, 0.f, 0.f},
        {0.244444444f, -0.933333333f, 0.888888889f, 0.f, 0.f},
        {0.738149672f, -2.898948331f, 2.455723213f, -0.072702332f, 0.f},
        {0.711568813f, -2.689393939f, 2.226605679f, 0.069602273f, -0.068382826f}};
    const float hB[6] = {0.022786458f, 0.f, 0.112309075f,
                         0.162760417f, -0.080593989f, 0.032738095f};

    auto pack2 = [&](const float* v) {
#pragma unroll
        for (int j = 0; j < 8; j++) { z0[j] = f2bf(v[j]); z1[j] = f2bf(v[8 + j]); }
    };
    auto readk = [&]() {
#pragma unroll
        for (int kt = 0; kt < 2; kt++) {
            floatx4 r0 = *(const floatx4*)&vbf[m * 68 + kt * 32 + kq * 8];
            floatx4 r1 = *(const floatx4*)&vbf[m * 68 + kt * 32 + kq * 8 + 4];
#pragma unroll
            for (int j = 0; j < 4; j++) { K[kt * 8 + j] = r0[j]; K[kt * 8 + 4 + j] = r1[j]; }
        }
    };

#pragma unroll 1
    for (int step = 0; step < 4; step++) {
        pack2(y);
#pragma unroll 1
        for (int s = 0; s < 6; s++) {
            float d = feval(z0, z1, e0, e1, ws, vb, tb);
            ylogp -= hB[s] * d;
            readk();
            if (s < 5) {
                // store K into slot s (packed bf16), static reg indexing
#pragma unroll
                for (int t = 0; t < 5; t++)
                    if (t == s) {
#pragma unroll
                        for (int j = 0; j < 8; j++) {
                            Ks[t][0][j] = f2bf(K[j]);
                            Ks[t][1][j] = f2bf(K[8 + j]);
                        }
                    }
                // z for next stage: y + sum_j hA[s][j] * k_{j+1}
#pragma unroll
                for (int i = 0; i < 16; i++) zs[i] = y[i] + hA[s][s] * K[i];
#pragma unroll
                for (int j = 0; j < 5; j++)
                    if (j < s) {
                        float c = hA[s][j];
#pragma unroll
                        for (int i = 0; i < 8; i++) {
                            zs[i]     += c * bf2f(Ks[j][0][i]);
                            zs[8 + i] += c * bf2f(Ks[j][1][i]);
                        }
                    }
                pack2(zs);
            }
        }
        // y update: k6 is in K; k1..k5 from packed slots (hB[1]=0 skips k2)
#pragma unroll
        for (int i = 0; i < 16; i++) y[i] += hB[5] * K[i];
#pragma unroll
        for (int j = 0; j < 5; j++)
            if (hB[j] != 0.f) {
                float c = hB[j];
#pragma unroll
                for (int i = 0; i < 8; i++) {
                    y[i]     += c * bf2f(Ks[j][0][i]);
                    y[8 + i] += c * bf2f(Ks[j][1][i]);
                }
            }
    }

    float nrm = 0.f;
#pragma unroll
    for (int i = 0; i < 16; i++) nrm += y[i] * y[i];
    nrm += __shfl_xor(nrm, 16, 64);
    nrm += __shfl_xor(nrm, 32, 64);
    float res = -0.5f * nrm - LOG2PI_HALF_SUM - ylogp;
    if (lane < 16) out[blockIdx.x * 32 + wave * 16 + lane] = res;
}

// ---- weight pre-shuffle: fp32 [N][K] -> bf16 fragment-linear ----
// frag = ktile*NT + ntile; lane l holds W[ntile*16+(l&15)][ktile*32+(l>>4)*8 + 0..7]
__global__ void prep_w(const float* __restrict__ W, short* __restrict__ outp,
                       int K, int NT, int KT) {
    int slot  = blockIdx.x * 256 + threadIdx.x;
    int total = KT * NT * 64;
    if (slot >= total) return;
    int lane  = slot & 63, frag = slot >> 6;
    int ntile = frag % NT, ktile = frag / NT;
    int n = ntile * 16 + (lane & 15);
    int k = ktile * 32 + (lane >> 4) * 8;
    short8 v;
#pragma unroll
    for (int j = 0; j < 8; j++) v[j] = f2bf(W[n * K + k + j]);
    *(short8*)(outp + slot * 8) = v;
}

__global__ void prep_b(const float* __restrict__ b1, const float* __restrict__ b2,
                       const float* __restrict__ b3, const float* __restrict__ b4,
                       float* __restrict__ dst) {
    int i = blockIdx.x * 256 + threadIdx.x;
    if (i < 256)      dst[i] = b1[i];
    else if (i < 512) dst[i] = b2[i - 256];
    else if (i < 768) dst[i] = b3[i - 512];
    else if (i < 832) dst[i] = b4[i - 768];
}

extern "C" void kernel_launch(void* const* d_in, const int* in_sizes, int n_in,
                              void* d_out, int out_size, void* d_ws, size_t ws_size,
                              hipStream_t stream) {
    const float* x   = (const float*)d_in[0];
    const float* eps = (const float*)d_in[1];
    const float* W1  = (const float*)d_in[2];
    const float* b1  = (const float*)d_in[3];
    const float* W2  = (const float*)d_in[4];
    const float* b2  = (const float*)d_in[5];
    const float* W3  = (const float*)d_in[6];
    const float* b3  = (const float*)d_in[7];
    const float* W4  = (const float*)d_in[8];
    const float* b4  = (const float*)d_in[9];
    char*  ws  = (char*)d_ws;
    float* out = (float*)d_out;

    prep_w<<<(2 * 16 * 64 + 255) / 256, 256, 0, stream>>>(W1, (short*)(ws + W1OFF), 64, 16, 2);
    prep_w<<<(8 * 16 * 64 + 255) / 256, 256, 0, stream>>>(W2, (short*)(ws + W2OFF), 256, 16, 8);
    prep_w<<<(8 * 16 * 64 + 255) / 256, 256, 0, stream>>>(W3, (short*)(ws + W3OFF), 256, 16, 8);
    prep_w<<<(8 * 4 * 64 + 255) / 256, 256, 0, stream>>>(W4, (short*)(ws + W4OFF), 256, 4, 8);
    prep_b<<<4, 256, 0, stream>>>(b1, b2, b3, b4, (float*)(ws + BOFF));

    cnf_main<<<BATCH / 32, 128, SMEM_BYTES, stream>>>(x, eps, ws, out);
}